// Round 11
// baseline (69.090 us; speedup 1.0000x reference)
//
#include <hip/hip_runtime.h>
#include <math.h>

#pragma clang fp contract(off)

#define LL 4096
#define FF 128
#define NB 32
#define BASE 16
#define NBLK 256
#define NOB 16

typedef float v2f __attribute__((ext_vector_type(2)));

__device__ __forceinline__ float sani(float v) {
    return (fabsf(v) <= 3.0e38f) ? v : 0.0f;
}

// ---------- K1: per-tile sequential totals (direct, coalesced) ----------
__global__ __launch_bounds__(256) void k_tiles(const float* __restrict__ x,
                                               float2* __restrict__ T0) {
    const int pair = (int)blockIdx.x;     // 0..127
    const int b    = (int)blockIdx.y;     // 0..31
    const int tid  = (int)threadIdx.x;
    const int f    = tid & 127;
    const int tile = pair * 2 + (tid >> 7);
    const float* xb = x + ((size_t)b * LL + (size_t)tile * 16) * FF + f;
    float cs, cs2;
    {
        const float v = sani(xb[0]);
        cs = v; cs2 = __fmul_rn(v, v);
    }
#pragma unroll
    for (int u = 1; u < 16; ++u) {
        const float v = sani(xb[(size_t)u * FF]);
        cs  = __fadd_rn(cs,  v);
        cs2 = __fadd_rn(cs2, __fmul_rn(v, v));
    }
    T0[((size_t)b * NBLK + tile) * FF + f] = make_float2(cs, cs2);
}

// ---------- K2a: in-place s1 (RN scan within each 16-group of T0) ----------
__global__ __launch_bounds__(128) void k_pref_a(float2* __restrict__ T0) {
    const int g = (int)blockIdx.x & 15;
    const int b = (int)blockIdx.x >> 4;   // grid 512 = 32*16
    const int f = (int)threadIdx.x;
    float2* p = T0 + ((size_t)b * NBLK + (size_t)g * 16) * FF + f;
    float2 t[16];
#pragma unroll
    for (int i = 0; i < 16; ++i) t[i] = p[(size_t)i * FF];
    float sx = t[0].x, sy = t[0].y;       // s1[0] = T0[0], already in place
#pragma unroll
    for (int i = 1; i < 16; ++i) {
        sx = __fadd_rn(sx, t[i].x);
        sy = __fadd_rn(sy, t[i].y);
        p[(size_t)i * FF] = make_float2(sx, sy);
    }
}

// ---------- K2b: S2 = RN scan of group totals ----------
__global__ __launch_bounds__(128) void k_pref_b(const float2* __restrict__ S1,
                                                float2* __restrict__ S2) {
    const int b = (int)blockIdx.x;        // 32
    const int f = (int)threadIdx.x;
    const float2* base = S1 + (size_t)b * NBLK * FF + f;
    float2* s2 = S2 + (size_t)b * NOB * FF + f;
    float2 t = base[(size_t)15 * FF];
    float sx = t.x, sy = t.y;
    s2[0] = t;
    for (int g = 1; g < NOB; ++g) {
        const float2 tg = base[(size_t)(g * 16 + 15) * FF];
        sx = __fadd_rn(sx, tg.x);
        sy = __fadd_rn(sy, tg.y);
        s2[(size_t)g * FF] = make_float2(sx, sy);
    }
}

// compose P for an f-pair (exact r6 op order): P[B] = s1[B] (+ RN S2[g-1])
__device__ __forceinline__ void compose_P(const float2* __restrict__ S1,
                                          const float2* __restrict__ S2,
                                          int b, int B, int f,
                                          v2f& pc, v2f& pq) {
    pc = (v2f)0.0f; pq = (v2f)0.0f;
    if (B < 0) return;
    const float4 q = *reinterpret_cast<const float4*>(S1 + ((size_t)b * NBLK + B) * FF + f);
    float c0 = q.x, q0 = q.y, c1 = q.z, q1 = q.w;
    const int g = B >> 4;
    if (g > 0) {
        const float4 s2 = *reinterpret_cast<const float4*>(S2 + ((size_t)b * NOB + (g - 1)) * FF + f);
        c0 = __fadd_rn(c0, s2.x); q0 = __fadd_rn(q0, s2.y);
        c1 = __fadd_rn(c1, s2.z); q1 = __fadd_rn(q1, s2.w);
    }
    pc.x = c0; pc.y = c1; pq.x = q0; pq.y = q1;
}

// ---------- K3: register V chains on f-pairs (packed f32), window phase ----------
template<bool GUARD>
__device__ __forceinline__ void win_body3(const float* __restrict__ xb,
                                          float* __restrict__ ob,
                                          const int base, const int lbase,
                                          const v2f PAc, const v2f PAq,
                                          const v2f PBc, const v2f PBq,
                                          const v2f PCc, const v2f PCq,
                                          const float ws0, const float ws1, const float ws2) {
    v2f Vx[41], Vy[41], xr[16];

#define SEG(P0, N, PC_, PQ_, SAVE)                                        \
    {                                                                     \
        v2f cs = (v2f)0.0f, cs2 = (v2f)0.0f;                              \
        _Pragma("unroll")                                                 \
        for (int u = 0; u < (N); ++u) {                                   \
            const int p = (P0) + u;                                       \
            v2f v = (v2f)0.0f;                                            \
            if (!GUARD || ((unsigned)(base + p) < (unsigned)LL)) {        \
                const float2 t = *reinterpret_cast<const float2*>(        \
                    xb + (p - 16) * FF);                                  \
                v.x = sani(t.x); v.y = sani(t.y);                         \
            }                                                             \
            if (SAVE) xr[u] = v;                                          \
            const v2f vq = v * v;                                         \
            if (u == 0) { cs = v; cs2 = vq; }                             \
            else        { cs = cs + v; cs2 = cs2 + vq; }                  \
            Vx[p] = cs + (PC_);                                           \
            Vy[p] = cs2 + (PQ_);                                          \
        }                                                                 \
    }
    SEG(0,  16, PAc, PAq, false)
    SEG(16, 16, PBc, PBq, true)
    SEG(32, 9,  PCc, PCq, false)
#undef SEG

#pragma unroll
    for (int u = 0; u < 16; ++u) {
        const int l = lbase + u;
        const v2f xc = xr[u];
        const float g5  = (l >= 2  && l <= LL - 3)  ? ws0 : 0.0f;
        const float g10 = (l >= 5  && l <= LL - 5)  ? ws1 : 0.0f;
        const float g20 = (l >= 10 && l <= LL - 10) ? ws2 : 0.0f;
        v2f o;
        {   // w=5:  cs_arr[l+3] -> pos u+18, cs_arr[l-2] -> pos u+13
            const v2f mean = (Vx[u + 18] - Vx[u + 13]) * 0.2f;
            const v2f m2   = (Vy[u + 18] - Vy[u + 13]) * 0.2f;
            const v2f var  = m2 - mean * mean;
            v2f inv;
            inv.x = rsqrtf(fmaxf(var.x, 0.0f) + 1e-5f);
            inv.y = rsqrtf(fmaxf(var.y, 0.0f) + 1e-5f);
            o = ((xc - mean) * inv) * g5;
        }
        {   // w=10: pos u+20 / u+10
            const v2f mean = (Vx[u + 20] - Vx[u + 10]) * 0.1f;
            const v2f m2   = (Vy[u + 20] - Vy[u + 10]) * 0.1f;
            const v2f var  = m2 - mean * mean;
            v2f inv;
            inv.x = rsqrtf(fmaxf(var.x, 0.0f) + 1e-5f);
            inv.y = rsqrtf(fmaxf(var.y, 0.0f) + 1e-5f);
            o = o + ((xc - mean) * inv) * g10;
        }
        {   // w=20: pos u+25 / u+5
            const v2f mean = (Vx[u + 25] - Vx[u + 5]) * 0.05f;
            const v2f m2   = (Vy[u + 25] - Vy[u + 5]) * 0.05f;
            const v2f var  = m2 - mean * mean;
            v2f inv;
            inv.x = rsqrtf(fmaxf(var.x, 0.0f) + 1e-5f);
            inv.y = rsqrtf(fmaxf(var.y, 0.0f) + 1e-5f);
            o = o + ((xc - mean) * inv) * g20;
        }
        *reinterpret_cast<float2*>(ob + (size_t)u * FF) = make_float2(o.x, o.y);
    }
}

__global__ __launch_bounds__(256) void k_win3(const float* __restrict__ x,
                                              const float* __restrict__ w,
                                              const float2* __restrict__ S1,
                                              const float2* __restrict__ S2,
                                              float* __restrict__ out) {
    const int qb  = (int)blockIdx.x;      // 0..63
    const int b   = (int)blockIdx.y;      // 0..31
    const int tid = (int)threadIdx.x;
    const int tile = qb * 4 + (tid >> 6); // wave-uniform
    const int f    = (tid & 63) * 2;
    const int lbase = tile * 16;
    const int base  = lbase - 16;

    // softmax over 3 weights (uniform)
    const float w0 = w[0], w1 = w[1], w2 = w[2];
    const float mx = fmaxf(w0, fmaxf(w1, w2));
    const float e0 = expf(w0 - mx), e1 = expf(w1 - mx), e2 = expf(w2 - mx);
    const float s  = e0 + e1 + e2;
    const float ws0 = e0 / s, ws1 = e1 / s, ws2 = e2 / s;

    v2f PAc, PAq, PBc, PBq, PCc, PCq;
    compose_P(S1, S2, b, tile - 2, f, PAc, PAq);
    compose_P(S1, S2, b, tile - 1, f, PBc, PBq);
    compose_P(S1, S2, b, tile,     f, PCc, PCq);

    const float* xb = x   + ((size_t)b * LL + lbase) * FF + f;
    float*       ob = out + ((size_t)b * LL + lbase) * FF + f;

    if (tile >= 1 && tile <= NBLK - 2)   // guards needed only for tiles 0, 255
        win_body3<false>(xb, ob, base, lbase, PAc, PAq, PBc, PBq, PCc, PCq, ws0, ws1, ws2);
    else
        win_body3<true >(xb, ob, base, lbase, PAc, PAq, PBc, PBq, PCc, PCq, ws0, ws1, ws2);
}

// ---------- fallback: verified single-kernel r6 (if ws too small) ----------
__global__ __launch_bounds__(256) void fan_blocked(const float* __restrict__ x,
                                                   const float* __restrict__ w,
                                                   float* __restrict__ out) {
    __shared__ float2 V[LL];
    __shared__ float2 T0s[NBLK];
    __shared__ float2 T1[NOB];
    __shared__ float2 S2[NOB];
    const int col = blockIdx.x;
    const int f   = col & (FF - 1);
    const int b   = col >> 7;
    const int tid = (int)threadIdx.x;
    const float* xcol = x   + (size_t)b * LL * FF + f;
    float*       ocol = out + (size_t)b * LL * FF + f;
    for (int l = tid; l < LL; l += 256) {
        const float v = sani(xcol[(size_t)l * FF]);
        V[l] = make_float2(v, __fmul_rn(v, v));
    }
    __syncthreads();
    {
        const int bse = tid * BASE;
        float cs = V[bse].x, cs2 = V[bse].y;
        for (int u = 1; u < BASE; ++u) {
            const float2 e = V[bse + u];
            cs = __fadd_rn(cs, e.x); cs2 = __fadd_rn(cs2, e.y);
            V[bse + u] = make_float2(cs, cs2);
        }
        T0s[tid] = make_float2(cs, cs2);
    }
    __syncthreads();
    if (tid < NOB) {
        const int bse = tid * BASE;
        float cs = T0s[bse].x, cs2 = T0s[bse].y;
        for (int u = 1; u < BASE; ++u) {
            const float2 e = T0s[bse + u];
            cs = __fadd_rn(cs, e.x); cs2 = __fadd_rn(cs2, e.y);
            T0s[bse + u] = make_float2(cs, cs2);
        }
        T1[tid] = make_float2(cs, cs2);
    }
    __syncthreads();
    if (tid == 0) {
        float cs = T1[0].x, cs2 = T1[0].y;
        S2[0] = T1[0];
        for (int o = 1; o < NOB; ++o) {
            cs = __fadd_rn(cs, T1[o].x); cs2 = __fadd_rn(cs2, T1[o].y);
            S2[o] = make_float2(cs, cs2);
        }
    }
    __syncthreads();
    {
        const int blk = tid;
        if (blk > 0) {
            const int B = blk - 1, ob2 = B >> 4;
            float2 Pp = T0s[B];
            if (ob2 > 0) {
                const float2 s2 = S2[ob2 - 1];
                Pp = make_float2(__fadd_rn(Pp.x, s2.x), __fadd_rn(Pp.y, s2.y));
            }
            const int bse = blk * BASE;
            for (int u = 0; u < BASE; ++u) {
                const float2 sv = V[bse + u];
                V[bse + u] = make_float2(__fadd_rn(sv.x, Pp.x), __fadd_rn(sv.y, Pp.y));
            }
        }
    }
    __syncthreads();
    const float w0 = w[0], w1 = w[1], w2 = w[2];
    const float mx = fmaxf(w0, fmaxf(w1, w2));
    const float e0 = expf(w0 - mx), e1 = expf(w1 - mx), e2 = expf(w2 - mx);
    const float s  = e0 + e1 + e2;
    const float ws0 = e0 / s, ws1 = e1 / s, ws2 = e2 / s;
    auto PV = [&](int j) -> float2 {
        if (j <= 0) return make_float2(0.0f, 0.0f);
        int idx = j - 1; if (idx > LL - 1) idx = LL - 1;
        return V[idx];
    };
    for (int l = tid; l < LL; l += 256) {
        const float xc = sani(xcol[(size_t)l * FF]);
        const float2 A5 = PV(l + 3), B5 = PV(l - 2);
        const float2 A10 = PV(l + 5), B10 = PV(l - 5);
        const float2 A20 = PV(l + 10), B20 = PV(l - 10);
        const float g5  = (l >= 2  && l <= LL - 3)  ? ws0 : 0.0f;
        const float g10 = (l >= 5  && l <= LL - 5)  ? ws1 : 0.0f;
        const float g20 = (l >= 10 && l <= LL - 10) ? ws2 : 0.0f;
        float o;
        {
            const float mean = (A5.x - B5.x) * 0.2f;
            const float m2   = (A5.y - B5.y) * 0.2f;
            const float var  = fmaxf(m2 - mean * mean, 0.0f);
            o = g5 * ((xc - mean) * rsqrtf(var + 1e-5f));
        }
        {
            const float mean = (A10.x - B10.x) * 0.1f;
            const float m2   = (A10.y - B10.y) * 0.1f;
            const float var  = fmaxf(m2 - mean * mean, 0.0f);
            o += g10 * ((xc - mean) * rsqrtf(var + 1e-5f));
        }
        {
            const float mean = (A20.x - B20.x) * 0.05f;
            const float m2   = (A20.y - B20.y) * 0.05f;
            const float var  = fmaxf(m2 - mean * mean, 0.0f);
            o += g20 * ((xc - mean) * rsqrtf(var + 1e-5f));
        }
        ocol[(size_t)l * FF] = o;
    }
}

extern "C" void kernel_launch(void* const* d_in, const int* in_sizes, int n_in,
                              void* d_out, int out_size, void* d_ws, size_t ws_size,
                              hipStream_t stream) {
    const float* x = (const float*)d_in[0];
    const float* w = (const float*)d_in[1];
    float* out     = (float*)d_out;

    const size_t t0_bytes = (size_t)NB * NBLK * FF * sizeof(float2);   // 8 MiB
    if (ws_size >= 2 * t0_bytes) {                                     // 16 MiB
        float2* T0 = (float2*)d_ws;                                    // becomes s1 in place
        float2* S2 = (float2*)((char*)d_ws + t0_bytes);                // 0.5 MiB
        k_tiles <<<dim3(128, NB), dim3(256), 0, stream>>>(x, T0);
        k_pref_a<<<dim3(NB * 16), dim3(128), 0, stream>>>(T0);
        k_pref_b<<<dim3(NB),      dim3(128), 0, stream>>>(T0, S2);
        k_win3  <<<dim3(64, NB),  dim3(256), 0, stream>>>(x, w, T0, S2, out);
    } else {
        fan_blocked<<<dim3(NB * FF), dim3(256), 0, stream>>>(x, w, out);
    }
}